// Round 8
// baseline (1026.772 us; speedup 1.0000x reference)
//
#include <hip/hip_runtime.h>
#include <hip/hip_fp16.h>

#define HIDDIM 256
#define NHEADS 8
#define SCORE_SHIFT 4.0f

struct __attribute__((aligned(8)))  half4s { __half2 a, b; };
struct __attribute__((aligned(16))) half8s { __half2 a, b, c, d; };

// ---------------- GEMM: C[M,N] = act(A[M,K] @ W[K,N] + bias[N]) ----------------
template <int HALF_OUT>
__global__ __launch_bounds__(256) void gemm_bias_act(
    const float* __restrict__ A, const float* __restrict__ W,
    const float* __restrict__ bias, void* __restrict__ Cv,
    int M, int N, int K, int act) {
  __shared__ float As[16][65];
  __shared__ float Bs[16][64];
  const int tid = threadIdx.x;
  const int bm = blockIdx.y * 64, bn = blockIdx.x * 64;
  const int tx = tid & 15, ty = tid >> 4;
  float acc[4][4] = {};
  for (int k0 = 0; k0 < K; k0 += 16) {
    {
      const int m = tid >> 2;
      const int k = (tid & 3) * 4;
      const int gm = bm + m;
      float4 v = make_float4(0.f, 0.f, 0.f, 0.f);
      if (gm < M) v = *(const float4*)(A + (size_t)gm * K + k0 + k);
      As[k + 0][m] = v.x; As[k + 1][m] = v.y; As[k + 2][m] = v.z; As[k + 3][m] = v.w;
    }
    {
      const int n = (tid & 15) * 4;
      const int k = tid >> 4;
      *(float4*)&Bs[k][n] = *(const float4*)(W + (size_t)(k0 + k) * N + bn + n);
    }
    __syncthreads();
    #pragma unroll
    for (int kk = 0; kk < 16; ++kk) {
      float a[4], b[4];
      #pragma unroll
      for (int i = 0; i < 4; ++i) a[i] = As[kk][ty * 4 + i];
      #pragma unroll
      for (int j = 0; j < 4; ++j) b[j] = Bs[kk][tx * 4 + j];
      #pragma unroll
      for (int i = 0; i < 4; ++i)
        #pragma unroll
        for (int j = 0; j < 4; ++j) acc[i][j] = fmaf(a[i], b[j], acc[i][j]);
    }
    __syncthreads();
  }
  #pragma unroll
  for (int i = 0; i < 4; ++i) {
    const int gm = bm + ty * 4 + i;
    if (gm >= M) continue;
    float v[4];
    #pragma unroll
    for (int j = 0; j < 4; ++j) {
      const int gn = bn + tx * 4 + j;
      v[j] = acc[i][j] + bias[gn];
      if (act == 1 && v[j] < 0.f) v[j] = 0.f;
    }
    if (HALF_OUT) {
      half4s hv;
      hv.a = __floats2half2_rn(v[0], v[1]);
      hv.b = __floats2half2_rn(v[2], v[3]);
      *(half4s*)((__half*)Cv + (size_t)gm * N + bn + tx * 4) = hv;
    } else {
      *(float4*)((float*)Cv + (size_t)gm * N + bn + tx * 4) =
          make_float4(v[0], v[1], v[2], v[3]);
    }
  }
}

// ---------------- CSR build (by destination; stores SRC and DST per slot) ----------------
__global__ __launch_bounds__(256) void count_deg(
    const int* __restrict__ ei, int* __restrict__ deg, int E, int Nn) {
  const int t = blockIdx.x * blockDim.x + threadIdx.x;
  const int ET = E + Nn;
  if (t >= ET) return;
  const int dst = (t < E) ? ei[E + t] : (t - E);
  atomicAdd(&deg[dst], 1);
}

__global__ __launch_bounds__(1024) void scan_deg(
    const int* __restrict__ deg, int* __restrict__ rowptr, int Nn) {
  __shared__ int wsum[16];
  __shared__ int carry_s;
  const int tid = threadIdx.x;
  const int wid = tid >> 6, lane = tid & 63;
  if (tid == 0) { carry_s = 0; rowptr[0] = 0; }
  __syncthreads();
  for (int base = 0; base < Nn; base += 1024) {
    const int i = base + tid;
    int s = (i < Nn) ? deg[i] : 0;
    #pragma unroll
    for (int off = 1; off < 64; off <<= 1) {
      int t = __shfl_up(s, off);
      if (lane >= off) s += t;
    }
    if (lane == 63) wsum[wid] = s;
    __syncthreads();
    if (wid == 0 && lane < 16) {
      int ws = wsum[lane];
      #pragma unroll
      for (int off = 1; off < 16; off <<= 1) {
        int t = __shfl_up(ws, off);
        if (lane >= off) ws += t;
      }
      wsum[lane] = ws;
    }
    __syncthreads();
    const int prefix = (wid > 0 ? wsum[wid - 1] : 0) + carry_s;
    if (i < Nn) rowptr[i + 1] = s + prefix;
    __syncthreads();
    if (tid == 0) carry_s += wsum[15];
    __syncthreads();
  }
}

__global__ __launch_bounds__(256) void fill_csr(
    const int* __restrict__ ei, const int* __restrict__ rowptr,
    int* __restrict__ cursor, int* __restrict__ csr, int* __restrict__ csrd,
    int E, int Nn) {
  const int t = blockIdx.x * blockDim.x + threadIdx.x;
  const int ET = E + Nn;
  if (t >= ET) return;
  int src, dst;
  if (t < E) { src = ei[t]; dst = ei[E + t]; }
  else { src = t - E; dst = t - E; }
  const int pos = atomicAdd(&cursor[dst], 1);
  csr[rowptr[dst] + pos] = src;
  csrd[rowptr[dst] + pos] = dst;
}

// ---------------- edge_wv: flat edge-parallel (2 edges/wave, 32 lanes each) ----------------
// CSR slot j: gather xl[src], xr[dst]; w = exp(score - SHIFT);
// write wbuf[j][h] (fp32) and wval[j][:] = w * xl (fp16, CSR-contiguous).
__global__ __launch_bounds__(256) void edge_wv(
    const __half* __restrict__ xl, const __half* __restrict__ xr,
    const int* __restrict__ csr, const int* __restrict__ csrd,
    const float* __restrict__ att,
    float* __restrict__ wbuf, __half* __restrict__ wval, int ET) {
  const int wave = (int)((blockIdx.x * (size_t)blockDim.x + threadIdx.x) >> 6);
  const int lane = threadIdx.x & 63;
  if (wave * 2 >= ET) return;
  int j = wave * 2 + (lane >> 5);
  if (j >= ET) j = ET - 1;                  // duplicate write, same value: benign
  const int l5 = lane & 31;
  const int src = csr[j];
  const int dst = csrd[j];

  const half8s ha = *((const half8s*)(xl + (size_t)src * HIDDIM) + l5);
  const half8s hb = *((const half8s*)(xr + (size_t)dst * HIDDIM) + l5);
  const float4 at0 = *((const float4*)(att + l5 * 8));
  const float4 at1 = *((const float4*)(att + l5 * 8 + 4));

  float a[8], b[8];
  {
    float2 f;
    f = __half22float2(ha.a); a[0] = f.x; a[1] = f.y;
    f = __half22float2(ha.b); a[2] = f.x; a[3] = f.y;
    f = __half22float2(ha.c); a[4] = f.x; a[5] = f.y;
    f = __half22float2(ha.d); a[6] = f.x; a[7] = f.y;
    f = __half22float2(hb.a); b[0] = f.x; b[1] = f.y;
    f = __half22float2(hb.b); b[2] = f.x; b[3] = f.y;
    f = __half22float2(hb.c); b[4] = f.x; b[5] = f.y;
    f = __half22float2(hb.d); b[6] = f.x; b[7] = f.y;
  }
  const float atv[8] = {at0.x, at0.y, at0.z, at0.w, at1.x, at1.y, at1.z, at1.w};
  float s = 0.f;
  #pragma unroll
  for (int k = 0; k < 8; ++k) {
    float v = a[k] + b[k];
    v = v >= 0.f ? v : 0.2f * v;
    s = fmaf(v, atv[k], s);
  }
  // 4-lane head-group reduce (channels 8*l5.. are within head l5>>2)
  s += __shfl_xor(s, 1);
  s += __shfl_xor(s, 2);
  const float w = __expf(s - SCORE_SHIFT);
  if ((l5 & 3) == 0) wbuf[(size_t)j * NHEADS + (l5 >> 2)] = w;
  half8s wv;
  wv.a = __floats2half2_rn(w * a[0], w * a[1]);
  wv.b = __floats2half2_rn(w * a[2], w * a[3]);
  wv.c = __floats2half2_rn(w * a[4], w * a[5]);
  wv.d = __floats2half2_rn(w * a[6], w * a[7]);
  *((half8s*)(wval + (size_t)j * HIDDIM) + l5) = wv;
}

// ---------------- node_sum: contiguous streaming reduce + epilogue ----------------
// wave per node; lanes 0-31 & 32-63 each handle alternating edges; lane covers 8 channels.
template <int MODE>
__global__ __launch_bounds__(256) void node_sum(
    const __half* __restrict__ wval, const float* __restrict__ wbuf,
    const int* __restrict__ rowptr, const float* __restrict__ bias,
    const float* __restrict__ lng, const float* __restrict__ lnb,
    const int* __restrict__ batch, float* __restrict__ pooled,
    float* __restrict__ counts, float* __restrict__ outp, int Nn) {
  const int n = (int)((blockIdx.x * (size_t)blockDim.x + threadIdx.x) >> 6);
  const int lane = threadIdx.x & 63;
  if (n >= Nn) return;
  const int r0 = rowptr[n], r1 = rowptr[n + 1];
  const int half_id = lane >> 5, l5 = lane & 31;

  float acc[8] = {};
  for (int jj = r0; jj < r1; jj += 4) {
    const int j0 = jj + half_id;
    const int j1 = j0 + 2;
    const bool v0 = j0 < r1, v1 = j1 < r1;
    const int c0 = v0 ? j0 : r1 - 1;
    const int c1 = v1 ? j1 : r1 - 1;
    const half8s h0 = *((const half8s*)(wval + (size_t)c0 * HIDDIM) + l5);
    const half8s h1 = *((const half8s*)(wval + (size_t)c1 * HIDDIM) + l5);
    if (v0) {
      float2 f;
      f = __half22float2(h0.a); acc[0] += f.x; acc[1] += f.y;
      f = __half22float2(h0.b); acc[2] += f.x; acc[3] += f.y;
      f = __half22float2(h0.c); acc[4] += f.x; acc[5] += f.y;
      f = __half22float2(h0.d); acc[6] += f.x; acc[7] += f.y;
    }
    if (v1) {
      float2 f;
      f = __half22float2(h1.a); acc[0] += f.x; acc[1] += f.y;
      f = __half22float2(h1.b); acc[2] += f.x; acc[3] += f.y;
      f = __half22float2(h1.c); acc[4] += f.x; acc[5] += f.y;
      f = __half22float2(h1.d); acc[6] += f.x; acc[7] += f.y;
    }
  }
  #pragma unroll
  for (int k = 0; k < 8; ++k) acc[k] += __shfl_xor(acc[k], 32);

  // denominator: lane covers flat indices f = lane, lane+64, ... ; head = f&7 = lane&7
  float den = 0.f;
  const int flat = (r1 - r0) * NHEADS;
  const float* wb = wbuf + (size_t)r0 * NHEADS;
  for (int f = lane; f < flat; f += 64) den += wb[f];
  den += __shfl_xor(den, 8);
  den += __shfl_xor(den, 16);
  den += __shfl_xor(den, 32);           // lanes 0..7 now hold den[head]
  const float dh = __shfl(den, l5 >> 2);
  const float inv_d = 1.f / dh;

  const float4 bb0 = *((const float4*)(bias + l5 * 8));
  const float4 bb1 = *((const float4*)(bias + l5 * 8 + 4));
  const float bv[8] = {bb0.x, bb0.y, bb0.z, bb0.w, bb1.x, bb1.y, bb1.z, bb1.w};
  float t[8];
  #pragma unroll
  for (int k = 0; k < 8; ++k) {
    t[k] = fmaf(acc[k], inv_d, bv[k]);
    t[k] = t[k] > 0.f ? t[k] : 0.f;
  }

  if (MODE == 0) {
    float s = 0.f;
    #pragma unroll
    for (int k = 0; k < 8; ++k) s += t[k];
    #pragma unroll
    for (int mm = 1; mm < 32; mm <<= 1) s += __shfl_xor(s, mm);
    const float mu = s * (1.f / HIDDIM);
    float q = 0.f;
    float dv[8];
    #pragma unroll
    for (int k = 0; k < 8; ++k) { dv[k] = t[k] - mu; q += dv[k] * dv[k]; }
    #pragma unroll
    for (int mm = 1; mm < 32; mm <<= 1) q += __shfl_xor(q, mm);
    const float inv = rsqrtf(q * (1.f / HIDDIM) + 1e-5f);
    const float4 g0 = *((const float4*)(lng + l5 * 8));
    const float4 g1 = *((const float4*)(lng + l5 * 8 + 4));
    const float4 p0 = *((const float4*)(lnb + l5 * 8));
    const float4 p1 = *((const float4*)(lnb + l5 * 8 + 4));
    const float gv[8] = {g0.x, g0.y, g0.z, g0.w, g1.x, g1.y, g1.z, g1.w};
    const float pv[8] = {p0.x, p0.y, p0.z, p0.w, p1.x, p1.y, p1.z, p1.w};
    if (half_id == 0) {
      float4 o0, o1;
      o0.x = dv[0] * inv * gv[0] + pv[0];
      o0.y = dv[1] * inv * gv[1] + pv[1];
      o0.z = dv[2] * inv * gv[2] + pv[2];
      o0.w = dv[3] * inv * gv[3] + pv[3];
      o1.x = dv[4] * inv * gv[4] + pv[4];
      o1.y = dv[5] * inv * gv[5] + pv[5];
      o1.z = dv[6] * inv * gv[6] + pv[6];
      o1.w = dv[7] * inv * gv[7] + pv[7];
      *((float4*)(outp + (size_t)n * HIDDIM + l5 * 8)) = o0;
      *((float4*)(outp + (size_t)n * HIDDIM + l5 * 8 + 4)) = o1;
    }
  } else {
    if (half_id == 0) {
      const int g = batch[n];
      float* p = pooled + (size_t)g * HIDDIM + l5 * 8;
      #pragma unroll
      for (int k = 0; k < 8; ++k) atomicAdd(p + k, t[k]);
      if (lane == 0) atomicAdd(&counts[g], 1.f);
    }
  }
}

// ---------------- fallback: R6 fused per-node kernel (fp16 xl rows) ----------------
template <int MODE>
__global__ __launch_bounds__(256) void node_gat(
    const __half* __restrict__ xl, const float* __restrict__ xr,
    const int* __restrict__ rowptr, const int* __restrict__ csr,
    const float* __restrict__ att, const float* __restrict__ bias,
    const float* __restrict__ lng, const float* __restrict__ lnb,
    const int* __restrict__ batch, float* __restrict__ pooled,
    float* __restrict__ counts, float* __restrict__ outp, int Nn) {
  int n = (int)((blockIdx.x * (size_t)blockDim.x + threadIdx.x) >> 6);
  const int lane = threadIdx.x & 63;
  if (n >= Nn) return;
  n = __builtin_amdgcn_readfirstlane(n);
  const int r0 = rowptr[n], r1 = rowptr[n + 1];
  const int jm = r1 - 1;
  const half4s* __restrict__ xlv = (const half4s*)xl;
  const float4 xr4 = *(const float4*)(xr + (size_t)n * HIDDIM + lane * 4);
  const float4 at4 = *(const float4*)(att + lane * 4);
  float m = -1e30f, d = 0.f;
  float4 acc = make_float4(0.f, 0.f, 0.f, 0.f);
  for (int j0 = r0; j0 <= jm; j0 += 8) {
    half4s r[8];
    #pragma unroll
    for (int k = 0; k < 8; ++k) {
      int j = j0 + k; j = j <= jm ? j : jm;
      r[k] = xlv[(size_t)csr[j] * (HIDDIM / 4) + lane];
    }
    float4 a[8];
    float s[8];
    #pragma unroll
    for (int k = 0; k < 8; ++k) {
      const float2 f01 = __half22float2(r[k].a);
      const float2 f23 = __half22float2(r[k].b);
      a[k] = make_float4(f01.x, f01.y, f23.x, f23.y);
      float v, ss;
      v = a[k].x + xr4.x; v = v >= 0.f ? v : 0.2f * v; ss = v * at4.x;
      v = a[k].y + xr4.y; v = v >= 0.f ? v : 0.2f * v; ss = fmaf(v, at4.y, ss);
      v = a[k].z + xr4.z; v = v >= 0.f ? v : 0.2f * v; ss = fmaf(v, at4.z, ss);
      v = a[k].w + xr4.w; v = v >= 0.f ? v : 0.2f * v; ss = fmaf(v, at4.w, ss);
      s[k] = ss;
    }
    #pragma unroll
    for (int k = 0; k < 8; ++k) {
      s[k] += __shfl_xor(s[k], 1);
      s[k] += __shfl_xor(s[k], 2);
      s[k] += __shfl_xor(s[k], 4);
      if (j0 + k > jm) s[k] = -1e30f;
    }
    float mb = m;
    #pragma unroll
    for (int k = 0; k < 8; ++k) mb = fmaxf(mb, s[k]);
    const float scale = __expf(m - mb);
    float w[8];
    float dsum = 0.f;
    #pragma unroll
    for (int k = 0; k < 8; ++k) { w[k] = __expf(s[k] - mb); dsum += w[k]; }
    d = fmaf(d, scale, dsum);
    float ax = acc.x * scale, ay = acc.y * scale, az = acc.z * scale, aw = acc.w * scale;
    #pragma unroll
    for (int k = 0; k < 8; ++k) {
      ax = fmaf(w[k], a[k].x, ax);
      ay = fmaf(w[k], a[k].y, ay);
      az = fmaf(w[k], a[k].z, az);
      aw = fmaf(w[k], a[k].w, aw);
    }
    acc = make_float4(ax, ay, az, aw);
    m = mb;
  }
  const float inv_d = 1.f / d;
  const float4 bb = *(const float4*)(bias + lane * 4);
  float t0 = fmaf(acc.x, inv_d, bb.x); t0 = t0 > 0.f ? t0 : 0.f;
  float t1 = fmaf(acc.y, inv_d, bb.y); t1 = t1 > 0.f ? t1 : 0.f;
  float t2 = fmaf(acc.z, inv_d, bb.z); t2 = t2 > 0.f ? t2 : 0.f;
  float t3 = fmaf(acc.w, inv_d, bb.w); t3 = t3 > 0.f ? t3 : 0.f;
  if (MODE == 0) {
    float s = t0 + t1 + t2 + t3;
    #pragma unroll
    for (int mm = 1; mm < 64; mm <<= 1) s += __shfl_xor(s, mm);
    const float mu = s * (1.f / HIDDIM);
    const float d0 = t0 - mu, d1 = t1 - mu, d2 = t2 - mu, d3 = t3 - mu;
    float q = d0 * d0 + d1 * d1 + d2 * d2 + d3 * d3;
    #pragma unroll
    for (int mm = 1; mm < 64; mm <<= 1) q += __shfl_xor(q, mm);
    const float inv = rsqrtf(q * (1.f / HIDDIM) + 1e-5f);
    const float4 g4 = *(const float4*)(lng + lane * 4);
    const float4 b4 = *(const float4*)(lnb + lane * 4);
    float4 o;
    o.x = d0 * inv * g4.x + b4.x;
    o.y = d1 * inv * g4.y + b4.y;
    o.z = d2 * inv * g4.z + b4.z;
    o.w = d3 * inv * g4.w + b4.w;
    *(float4*)(outp + (size_t)n * HIDDIM + lane * 4) = o;
  } else {
    const int g = batch[n];
    float* p = pooled + (size_t)g * HIDDIM + lane * 4;
    atomicAdd(p + 0, t0);
    atomicAdd(p + 1, t1);
    atomicAdd(p + 2, t2);
    atomicAdd(p + 3, t3);
    if (lane == 0) atomicAdd(&counts[g], 1.f);
  }
}

// ---------------- head MLP ----------------
__global__ __launch_bounds__(256) void head_kernel(
    const float* __restrict__ pooled, const float* __restrict__ counts,
    const float* __restrict__ h1w, const float* __restrict__ h1b,
    const float* __restrict__ h2w, const float* __restrict__ h2b,
    float* __restrict__ out, int G, int H1, int OUT) {
  __shared__ float P[16][HIDDIM];
  __shared__ float Hh[16][128];
  const int tid = threadIdx.x;
  for (int i = tid; i < G * HIDDIM; i += 256) {
    const int g = i / HIDDIM, c = i % HIDDIM;
    float cnt = counts[g];
    if (cnt < 1.f) cnt = 1.f;
    P[g][c] = pooled[i] / cnt;
  }
  __syncthreads();
  for (int i = tid; i < G * H1; i += 256) {
    const int g = i / H1, j = i % H1;
    float s = h1b[j];
    for (int k = 0; k < HIDDIM; ++k) s = fmaf(P[g][k], h1w[k * H1 + j], s);
    Hh[g][j] = s > 0.f ? s : 0.f;
  }
  __syncthreads();
  for (int i = tid; i < G * OUT; i += 256) {
    const int g = i / OUT, o = i % OUT;
    float s = h2b[o];
    for (int k = 0; k < H1; ++k) s = fmaf(Hh[g][k], h2w[k * OUT + o], s);
    out[i] = s;
  }
}

extern "C" void kernel_launch(void* const* d_in, const int* in_sizes, int n_in,
                              void* d_out, int out_size, void* d_ws, size_t ws_size,
                              hipStream_t stream) {
  const float* x = (const float*)d_in[0];
  const int* ei = (const int*)d_in[1];
  const int* batch = (const int*)d_in[2];
  const float* enc_w = (const float*)d_in[3];
  const float* enc_b = (const float*)d_in[4];
  const float* g_wl[2] = {(const float*)d_in[5], (const float*)d_in[11]};
  const float* g_bl[2] = {(const float*)d_in[6], (const float*)d_in[12]};
  const float* g_wr[2] = {(const float*)d_in[7], (const float*)d_in[13]};
  const float* g_br[2] = {(const float*)d_in[8], (const float*)d_in[14]};
  const float* g_att[2] = {(const float*)d_in[9], (const float*)d_in[15]};
  const float* g_bias[2] = {(const float*)d_in[10], (const float*)d_in[16]};
  const float* ln_g = (const float*)d_in[17];
  const float* ln_b = (const float*)d_in[18];
  const float* h1_w = (const float*)d_in[19];
  const float* h1_b = (const float*)d_in[20];
  const float* h2_w = (const float*)d_in[21];
  const float* h2_b = (const float*)d_in[22];
  float* out = (float*)d_out;

  const int N = in_sizes[2];          // 20000
  const int E = in_sizes[1] / 2;      // 320000
  const int DIN = in_sizes[0] / N;    // 128
  const int ET = E + N;
  const int H1 = in_sizes[20];        // 128
  const int OUT = in_sizes[22];       // 2
  const int G = out_size / OUT;       // 16

  char* base = (char*)d_ws;
  const size_t NH = (size_t)N * HIDDIM;
  const size_t NHb = NH * sizeof(float);
  float*  h0   = (float*)base;                       // [N][256] f32
  float*  xrf  = (float*)(base + NHb);               // fallback xr f32
  __half* xl16 = (__half*)(base + 2 * NHb);          // [N][256] f16
  __half* xr16 = (__half*)(base + 2 * NHb + NH * 2); // [N][256] f16 (new path)
  float*  pooled = (float*)(base + 3 * NHb);
  float*  counts = pooled + (size_t)G * HIDDIM;
  int* deg    = (int*)(counts + G);
  int* rowptr = deg + N;
  int* cursor = rowptr + (N + 1);
  int* csr    = cursor + N;
  int* csrd   = csr + ET;
  size_t bigoff = (size_t)((char*)(csrd + ET) - base);
  bigoff = (bigoff + 255) & ~(size_t)255;
  __half* wval = (__half*)(base + bigoff);                       // [ET][256] f16
  float*  wbuf = (float*)(base + bigoff + (size_t)ET * HIDDIM * 2); // [ET][8] f32
  const size_t need = bigoff + (size_t)ET * HIDDIM * 2 + (size_t)ET * NHEADS * 4;
  const bool newpath = ws_size >= need;

  const dim3 blk(256);
  const dim3 gemm_grid(HIDDIM / 64, (N + 63) / 64);
  const int eb = (ET + 255) / 256;
  const int nb = (N + 3) / 4;
  const int wb = (int)(((size_t)(ET + 1) / 2 + 3) / 4);

  // CSR build (graph identical for both layers)
  hipMemsetAsync(deg, 0, (size_t)N * sizeof(int), stream);
  hipMemsetAsync(cursor, 0, (size_t)N * sizeof(int), stream);
  hipMemsetAsync(pooled, 0, ((size_t)G * HIDDIM + G) * sizeof(float), stream);
  count_deg<<<eb, blk, 0, stream>>>(ei, deg, E, N);
  scan_deg<<<1, 1024, 0, stream>>>(deg, rowptr, N);
  fill_csr<<<eb, blk, 0, stream>>>(ei, rowptr, cursor, csr, csrd, E, N);

  // encoder
  gemm_bias_act<0><<<gemm_grid, blk, 0, stream>>>(x, enc_w, enc_b, h0, N, HIDDIM, DIN, 1);

  for (int L = 0; L < 2; ++L) {
    gemm_bias_act<1><<<gemm_grid, blk, 0, stream>>>(h0, g_wl[L], g_bl[L], xl16, N, HIDDIM, HIDDIM, 0);
    if (newpath) {
      gemm_bias_act<1><<<gemm_grid, blk, 0, stream>>>(h0, g_wr[L], g_br[L], xr16, N, HIDDIM, HIDDIM, 0);
      edge_wv<<<wb, blk, 0, stream>>>(xl16, xr16, csr, csrd, g_att[L], wbuf, wval, ET);
      if (L == 0) {
        node_sum<0><<<nb, blk, 0, stream>>>(wval, wbuf, rowptr, g_bias[0],
                                            ln_g, ln_b, nullptr, nullptr, nullptr, h0, N);
      } else {
        node_sum<1><<<nb, blk, 0, stream>>>(wval, wbuf, rowptr, g_bias[1],
                                            nullptr, nullptr, batch, pooled, counts, nullptr, N);
      }
    } else {
      gemm_bias_act<0><<<gemm_grid, blk, 0, stream>>>(h0, g_wr[L], g_br[L], xrf, N, HIDDIM, HIDDIM, 0);
      if (L == 0) {
        node_gat<0><<<nb, blk, 0, stream>>>(xl16, xrf, rowptr, csr, g_att[0], g_bias[0],
                                            ln_g, ln_b, nullptr, nullptr, nullptr, h0, N);
      } else {
        node_gat<1><<<nb, blk, 0, stream>>>(xl16, xrf, rowptr, csr, g_att[1], g_bias[1],
                                            nullptr, nullptr, batch, pooled, counts, nullptr, N);
      }
    }
  }
  head_kernel<<<1, blk, 0, stream>>>(pooled, counts, h1_w, h1_b, h2_w, h2_b, out, G, H1, OUT);
}

// Round 9
// 650.738 us; speedup vs baseline: 1.5779x; 1.5779x over previous
//
#include <hip/hip_runtime.h>
#include <hip/hip_fp16.h>

#define HIDDIM 256
#define NHEADS 8

struct __attribute__((aligned(8))) half4s { __half2 a, b; };

typedef _Float16 f16x8 __attribute__((ext_vector_type(8)));
typedef float f32x4 __attribute__((ext_vector_type(4)));

// ---------------- converts ----------------
__global__ __launch_bounds__(256) void cvt_f2h(
    const float* __restrict__ in, __half* __restrict__ out, int n) {
  const int i = blockIdx.x * 256 + threadIdx.x;
  if (i < n) out[i] = __float2half(in[i]);
}

// in [K][N] fp32 -> out [N][K] fp16 (transposed)
__global__ __launch_bounds__(256) void cvt_transpose(
    const float* __restrict__ in, __half* __restrict__ out, int K, int N) {
  const int idx = blockIdx.x * 256 + threadIdx.x;
  if (idx >= K * N) return;
  const int n = idx / K, k = idx - n * K;
  out[idx] = __float2half(in[(size_t)k * N + n]);
}

// ---------------- MFMA GEMM: C16[M,N] = act(A16[M,K] @ Wt16[N,K]^T + bias) ----------------
// block 256 = 4 waves; per block 64 rows x 64 cols; wave = 16 rows x 64 cols.
// frag layout (gfx950 16x16x32): A: row=lane&15, k=(lane>>4)*8+j ; B: col=lane&15, same k.
// C/D: col=lane&15, row=(lane>>4)*4+reg  [HW-verified mapping]
template <int RELU>
__global__ __launch_bounds__(256) void gemm_mfma(
    const _Float16* __restrict__ A, const _Float16* __restrict__ Wt,
    const float* __restrict__ bias, _Float16* __restrict__ C,
    int M, int N, int K) {
  const int wv = threadIdx.x >> 6;
  const int lane = threadIdx.x & 63;
  const int bn = blockIdx.x * 64;
  const int bm = blockIdx.y * 64 + wv * 16;
  const int fr = lane & 15;        // A-row / B-col within tile
  const int kb = lane >> 4;        // k-block (0..3), 8 elems each

  int arow = bm + fr; if (arow >= M) arow = M - 1;   // clamp; stores guarded
  const _Float16* ap = A + (size_t)arow * K + kb * 8;
  const _Float16* bp = Wt + (size_t)(bn + fr) * K + kb * 8;

  f32x4 acc[4] = {};
  for (int k0 = 0; k0 < K; k0 += 32) {
    const f16x8 a = *(const f16x8*)(ap + k0);
    #pragma unroll
    for (int nt = 0; nt < 4; ++nt) {
      const f16x8 b = *(const f16x8*)(bp + (size_t)nt * 16 * K + k0);
      acc[nt] = __builtin_amdgcn_mfma_f32_16x16x32_f16(a, b, acc[nt], 0, 0, 0);
    }
  }
  #pragma unroll
  for (int r = 0; r < 4; ++r) {
    const int row = bm + (lane >> 4) * 4 + r;
    if (row >= M) continue;
    #pragma unroll
    for (int nt = 0; nt < 4; ++nt) {
      const int col = bn + nt * 16 + fr;
      float v = acc[nt][r] + bias[col];
      if (RELU && v < 0.f) v = 0.f;
      C[(size_t)row * N + col] = (_Float16)v;
    }
  }
}

// ---------------- CSR build (by destination; stores SRC node id) ----------------
__global__ __launch_bounds__(256) void count_deg(
    const int* __restrict__ ei, int* __restrict__ deg, int E, int Nn) {
  const int t = blockIdx.x * blockDim.x + threadIdx.x;
  const int ET = E + Nn;
  if (t >= ET) return;
  const int dst = (t < E) ? ei[E + t] : (t - E);
  atomicAdd(&deg[dst], 1);
}

__global__ __launch_bounds__(1024) void scan_deg(
    const int* __restrict__ deg, int* __restrict__ rowptr, int Nn) {
  __shared__ int wsum[16];
  __shared__ int carry_s;
  const int tid = threadIdx.x;
  const int wid = tid >> 6, lane = tid & 63;
  if (tid == 0) { carry_s = 0; rowptr[0] = 0; }
  __syncthreads();
  for (int base = 0; base < Nn; base += 1024) {
    const int i = base + tid;
    int s = (i < Nn) ? deg[i] : 0;
    #pragma unroll
    for (int off = 1; off < 64; off <<= 1) {
      int t = __shfl_up(s, off);
      if (lane >= off) s += t;
    }
    if (lane == 63) wsum[wid] = s;
    __syncthreads();
    if (wid == 0 && lane < 16) {
      int ws = wsum[lane];
      #pragma unroll
      for (int off = 1; off < 16; off <<= 1) {
        int t = __shfl_up(ws, off);
        if (lane >= off) ws += t;
      }
      wsum[lane] = ws;
    }
    __syncthreads();
    const int prefix = (wid > 0 ? wsum[wid - 1] : 0) + carry_s;
    if (i < Nn) rowptr[i + 1] = s + prefix;
    __syncthreads();
    if (tid == 0) carry_s += wsum[15];
    __syncthreads();
  }
}

__global__ __launch_bounds__(256) void fill_csr(
    const int* __restrict__ ei, const int* __restrict__ rowptr,
    int* __restrict__ cursor, int* __restrict__ csr, int E, int Nn) {
  const int t = blockIdx.x * blockDim.x + threadIdx.x;
  const int ET = E + Nn;
  if (t >= ET) return;
  int src, dst;
  if (t < E) { src = ei[t]; dst = ei[E + t]; }
  else { src = t - E; dst = t - E; }
  const int pos = atomicAdd(&cursor[dst], 1);
  csr[rowptr[dst] + pos] = src;
}

// ---------------- fused single-pass GATv2 per-node (fp16 xl & xr rows) ----------------
// one wave per node; lane covers channels [4*lane,4*lane+4); head h = lane>>3
template <int MODE>
__global__ __launch_bounds__(256) void node_gat(
    const __half* __restrict__ xl, const __half* __restrict__ xr,
    const int* __restrict__ rowptr, const int* __restrict__ csr,
    const float* __restrict__ att, const float* __restrict__ bias,
    const float* __restrict__ lng, const float* __restrict__ lnb,
    const int* __restrict__ batch, float* __restrict__ pooled,
    float* __restrict__ counts, __half* __restrict__ outp, int Nn) {
  int n = (int)((blockIdx.x * (size_t)blockDim.x + threadIdx.x) >> 6);
  const int lane = threadIdx.x & 63;
  if (n >= Nn) return;
  n = __builtin_amdgcn_readfirstlane(n);
  const int r0 = rowptr[n], r1 = rowptr[n + 1];
  const int jm = r1 - 1;
  const half4s* __restrict__ xlv = (const half4s*)xl;
  float4 xr4;
  {
    const half4s xrh = *((const half4s*)xr + (size_t)n * (HIDDIM / 4) + lane);
    const float2 f01 = __half22float2(xrh.a);
    const float2 f23 = __half22float2(xrh.b);
    xr4 = make_float4(f01.x, f01.y, f23.x, f23.y);
  }
  const float4 at4 = *(const float4*)(att + lane * 4);
  float m = -1e30f, d = 0.f;
  float4 acc = make_float4(0.f, 0.f, 0.f, 0.f);

  for (int j0 = r0; j0 <= jm; j0 += 8) {
    half4s r[8];
    #pragma unroll
    for (int k = 0; k < 8; ++k) {
      int j = j0 + k; j = j <= jm ? j : jm;
      r[k] = xlv[(size_t)csr[j] * (HIDDIM / 4) + lane];
    }
    float4 a[8];
    float s[8];
    #pragma unroll
    for (int k = 0; k < 8; ++k) {
      const float2 f01 = __half22float2(r[k].a);
      const float2 f23 = __half22float2(r[k].b);
      a[k] = make_float4(f01.x, f01.y, f23.x, f23.y);
      float v, ss;
      v = a[k].x + xr4.x; v = v >= 0.f ? v : 0.2f * v; ss = v * at4.x;
      v = a[k].y + xr4.y; v = v >= 0.f ? v : 0.2f * v; ss = fmaf(v, at4.y, ss);
      v = a[k].z + xr4.z; v = v >= 0.f ? v : 0.2f * v; ss = fmaf(v, at4.z, ss);
      v = a[k].w + xr4.w; v = v >= 0.f ? v : 0.2f * v; ss = fmaf(v, at4.w, ss);
      s[k] = ss;
    }
    #pragma unroll
    for (int k = 0; k < 8; ++k) {
      s[k] += __shfl_xor(s[k], 1);
      s[k] += __shfl_xor(s[k], 2);
      s[k] += __shfl_xor(s[k], 4);
      if (j0 + k > jm) s[k] = -1e30f;
    }
    float mb = m;
    #pragma unroll
    for (int k = 0; k < 8; ++k) mb = fmaxf(mb, s[k]);
    const float scale = __expf(m - mb);
    float w[8];
    float dsum = 0.f;
    #pragma unroll
    for (int k = 0; k < 8; ++k) { w[k] = __expf(s[k] - mb); dsum += w[k]; }
    d = fmaf(d, scale, dsum);
    float ax = acc.x * scale, ay = acc.y * scale, az = acc.z * scale, aw = acc.w * scale;
    #pragma unroll
    for (int k = 0; k < 8; ++k) {
      ax = fmaf(w[k], a[k].x, ax);
      ay = fmaf(w[k], a[k].y, ay);
      az = fmaf(w[k], a[k].z, az);
      aw = fmaf(w[k], a[k].w, aw);
    }
    acc = make_float4(ax, ay, az, aw);
    m = mb;
  }
  const float inv_d = 1.f / d;
  const float4 bb = *(const float4*)(bias + lane * 4);
  float t0 = fmaf(acc.x, inv_d, bb.x); t0 = t0 > 0.f ? t0 : 0.f;
  float t1 = fmaf(acc.y, inv_d, bb.y); t1 = t1 > 0.f ? t1 : 0.f;
  float t2 = fmaf(acc.z, inv_d, bb.z); t2 = t2 > 0.f ? t2 : 0.f;
  float t3 = fmaf(acc.w, inv_d, bb.w); t3 = t3 > 0.f ? t3 : 0.f;

  if (MODE == 0) {
    float s = t0 + t1 + t2 + t3;
    #pragma unroll
    for (int mm = 1; mm < 64; mm <<= 1) s += __shfl_xor(s, mm);
    const float mu = s * (1.f / HIDDIM);
    const float d0 = t0 - mu, d1 = t1 - mu, d2 = t2 - mu, d3 = t3 - mu;
    float q = d0 * d0 + d1 * d1 + d2 * d2 + d3 * d3;
    #pragma unroll
    for (int mm = 1; mm < 64; mm <<= 1) q += __shfl_xor(q, mm);
    const float inv = rsqrtf(q * (1.f / HIDDIM) + 1e-5f);
    const float4 g4 = *(const float4*)(lng + lane * 4);
    const float4 b4 = *(const float4*)(lnb + lane * 4);
    half4s ho;
    ho.a = __floats2half2_rn(d0 * inv * g4.x + b4.x, d1 * inv * g4.y + b4.y);
    ho.b = __floats2half2_rn(d2 * inv * g4.z + b4.z, d3 * inv * g4.w + b4.w);
    *((half4s*)outp + (size_t)n * (HIDDIM / 4) + lane) = ho;
  } else {
    const int g = batch[n];
    float* p = pooled + (size_t)g * HIDDIM + lane * 4;
    atomicAdd(p + 0, t0);
    atomicAdd(p + 1, t1);
    atomicAdd(p + 2, t2);
    atomicAdd(p + 3, t3);
    if (lane == 0) atomicAdd(&counts[g], 1.f);
  }
}

// ---------------- head MLP ----------------
__global__ __launch_bounds__(256) void head_kernel(
    const float* __restrict__ pooled, const float* __restrict__ counts,
    const float* __restrict__ h1w, const float* __restrict__ h1b,
    const float* __restrict__ h2w, const float* __restrict__ h2b,
    float* __restrict__ out, int G, int H1, int OUT) {
  __shared__ float P[16][HIDDIM];
  __shared__ float Hh[16][128];
  const int tid = threadIdx.x;
  for (int i = tid; i < G * HIDDIM; i += 256) {
    const int g = i / HIDDIM, c = i % HIDDIM;
    float cnt = counts[g];
    if (cnt < 1.f) cnt = 1.f;
    P[g][c] = pooled[i] / cnt;
  }
  __syncthreads();
  for (int i = tid; i < G * H1; i += 256) {
    const int g = i / H1, j = i % H1;
    float s = h1b[j];
    for (int k = 0; k < HIDDIM; ++k) s = fmaf(P[g][k], h1w[k * H1 + j], s);
    Hh[g][j] = s > 0.f ? s : 0.f;
  }
  __syncthreads();
  for (int i = tid; i < G * OUT; i += 256) {
    const int g = i / OUT, o = i % OUT;
    float s = h2b[o];
    for (int k = 0; k < H1; ++k) s = fmaf(Hh[g][k], h2w[k * OUT + o], s);
    out[i] = s;
  }
}

extern "C" void kernel_launch(void* const* d_in, const int* in_sizes, int n_in,
                              void* d_out, int out_size, void* d_ws, size_t ws_size,
                              hipStream_t stream) {
  const float* x = (const float*)d_in[0];
  const int* ei = (const int*)d_in[1];
  const int* batch = (const int*)d_in[2];
  const float* enc_w = (const float*)d_in[3];
  const float* enc_b = (const float*)d_in[4];
  const float* g_wl[2] = {(const float*)d_in[5], (const float*)d_in[11]};
  const float* g_bl[2] = {(const float*)d_in[6], (const float*)d_in[12]};
  const float* g_wr[2] = {(const float*)d_in[7], (const float*)d_in[13]};
  const float* g_br[2] = {(const float*)d_in[8], (const float*)d_in[14]};
  const float* g_att[2] = {(const float*)d_in[9], (const float*)d_in[15]};
  const float* g_bias[2] = {(const float*)d_in[10], (const float*)d_in[16]};
  const float* ln_g = (const float*)d_in[17];
  const float* ln_b = (const float*)d_in[18];
  const float* h1_w = (const float*)d_in[19];
  const float* h1_b = (const float*)d_in[20];
  const float* h2_w = (const float*)d_in[21];
  const float* h2_b = (const float*)d_in[22];
  float* out = (float*)d_out;

  const int N = in_sizes[2];          // 20000
  const int E = in_sizes[1] / 2;      // 320000
  const int DIN = in_sizes[0] / N;    // 128
  const int ET = E + N;
  const int H1 = in_sizes[20];        // 128
  const int OUT = in_sizes[22];       // 2
  const int G = out_size / OUT;       // 16

  char* base = (char*)d_ws;
  const size_t NH = (size_t)N * HIDDIM;
  __half* h16  = (__half*)base;                    // [N][256]
  __half* xl16 = h16 + NH;
  __half* xr16 = xl16 + NH;
  __half* x16  = xr16 + NH;                        // [N][DIN]
  __half* wtE  = x16 + (size_t)N * DIN;            // [256][DIN]
  __half* wt[4];
  wt[0] = wtE + (size_t)HIDDIM * DIN;              // [256][256] x4
  wt[1] = wt[0] + (size_t)HIDDIM * HIDDIM;
  wt[2] = wt[1] + (size_t)HIDDIM * HIDDIM;
  wt[3] = wt[2] + (size_t)HIDDIM * HIDDIM;
  float* pooled = (float*)(wt[3] + (size_t)HIDDIM * HIDDIM);
  float* counts = pooled + (size_t)G * HIDDIM;
  int* deg    = (int*)(counts + G);
  int* rowptr = deg + N;
  int* cursor = rowptr + (N + 1);
  int* csr    = cursor + N;

  const dim3 blk(256);
  const int eb = (ET + 255) / 256;
  const int nb = (N + 3) / 4;
  const dim3 mfma_grid(HIDDIM / 64, (N + 63) / 64);

  // CSR build (graph identical for both layers)
  hipMemsetAsync(deg, 0, (size_t)N * sizeof(int), stream);
  hipMemsetAsync(cursor, 0, (size_t)N * sizeof(int), stream);
  hipMemsetAsync(pooled, 0, ((size_t)G * HIDDIM + G) * sizeof(float), stream);
  count_deg<<<eb, blk, 0, stream>>>(ei, deg, E, N);
  scan_deg<<<1, 1024, 0, stream>>>(deg, rowptr, N);
  fill_csr<<<eb, blk, 0, stream>>>(ei, rowptr, cursor, csr, E, N);

  // weight/input conversion
  cvt_f2h<<<(N * DIN + 255) / 256, blk, 0, stream>>>(x, x16, N * DIN);
  cvt_transpose<<<(DIN * HIDDIM + 255) / 256, blk, 0, stream>>>(enc_w, wtE, DIN, HIDDIM);
  cvt_transpose<<<(HIDDIM * HIDDIM + 255) / 256, blk, 0, stream>>>(g_wl[0], wt[0], HIDDIM, HIDDIM);
  cvt_transpose<<<(HIDDIM * HIDDIM + 255) / 256, blk, 0, stream>>>(g_wr[0], wt[1], HIDDIM, HIDDIM);
  cvt_transpose<<<(HIDDIM * HIDDIM + 255) / 256, blk, 0, stream>>>(g_wl[1], wt[2], HIDDIM, HIDDIM);
  cvt_transpose<<<(HIDDIM * HIDDIM + 255) / 256, blk, 0, stream>>>(g_wr[1], wt[3], HIDDIM, HIDDIM);

  // encoder: h16 = relu(x @ enc_w + enc_b)
  gemm_mfma<1><<<mfma_grid, blk, 0, stream>>>(
      (const _Float16*)x16, (const _Float16*)wtE, enc_b, (_Float16*)h16, N, HIDDIM, DIN);

  for (int L = 0; L < 2; ++L) {
    gemm_mfma<0><<<mfma_grid, blk, 0, stream>>>(
        (const _Float16*)h16, (const _Float16*)wt[2 * L + 0], g_bl[L], (_Float16*)xl16, N, HIDDIM, HIDDIM);
    gemm_mfma<0><<<mfma_grid, blk, 0, stream>>>(
        (const _Float16*)h16, (const _Float16*)wt[2 * L + 1], g_br[L], (_Float16*)xr16, N, HIDDIM, HIDDIM);
    if (L == 0) {
      node_gat<0><<<nb, blk, 0, stream>>>(xl16, xr16, rowptr, csr, g_att[0], g_bias[0],
                                          ln_g, ln_b, nullptr, nullptr, nullptr, h16, N);
    } else {
      node_gat<1><<<nb, blk, 0, stream>>>(xl16, xr16, rowptr, csr, g_att[1], g_bias[1],
                                          nullptr, nullptr, batch, pooled, counts, nullptr, N);
    }
  }
  head_kernel<<<1, blk, 0, stream>>>(pooled, counts, h1_w, h1_b, h2_w, h2_b, out, G, H1, OUT);
}